// Round 5
// baseline (844.056 us; speedup 1.0000x reference)
//
#include <hip/hip_runtime.h>
#include <hip/hip_bf16.h>
#include <math.h>

#define B_ROWS 16384
#define DM 512
#define DFF 2048
#define DOUT 256
#define EPSV 1e-5f

typedef __hip_bfloat16 bf16;
typedef __attribute__((ext_vector_type(8))) short short8;
typedef __attribute__((ext_vector_type(4))) float f32x4;

__device__ __forceinline__ float gelu_f(float x) {
    return 0.5f * x * (1.0f + erff(x * 0.70710678118654752f));
}

__device__ __forceinline__ void gload16(const void* g, void* l) {
    __builtin_amdgcn_global_load_lds((const __attribute__((address_space(1))) void*)g,
                                     (__attribute__((address_space(3))) void*)l, 16, 0, 0);
}

// bijective XCD swizzle; requires nwg % 8 == 0 (all our grids satisfy this)
__device__ __forceinline__ int xcd_swz(int bid, int nwg) {
    const int cpx = nwg >> 3;
    return (bid & 7) * cpx + (bid >> 3);
}

// C = A(MxK,row) @ B(KxN) + bias, B given as BT (NxK,row). bf16 in, fp32 accum.
// 128x128 tile, BK=32, 4 waves, mfma 16x16x32 bf16.
template<bool GELU, bool OUTF, bool OUTB>
__global__ __launch_bounds__(256, 2)
void gemm_kernel(const bf16* __restrict__ A, const bf16* __restrict__ BT,
                 const float* __restrict__ bias,
                 float* __restrict__ Cf, bf16* __restrict__ Cb,
                 int M, int N, int K)
{
    __shared__ __align__(16) bf16 lA[128 * 32];
    __shared__ __align__(16) bf16 lB[128 * 32];

    const int t    = threadIdx.x;
    const int lane = t & 63;
    const int w    = t >> 6;
    const int wr   = w >> 1, wc = w & 1;
    const int fr   = lane & 15, kg = lane >> 4;

    int bid = xcd_swz(blockIdx.y * gridDim.x + blockIdx.x, gridDim.x * gridDim.y);
    const int bx = bid % gridDim.x, by = bid / gridDim.x;
    const long bm = (long)by * 128;
    const long bn = (long)bx * 128;

    const int lr = t >> 2;           // 0..63
    const int lc = (t & 3) * 8;      // 0,8,16,24

    const bf16* Ag0 = A + (bm + lr) * (long)K + lc;
    const bf16* Ag1 = Ag0 + 64L * K;
    const bf16* Bg0 = BT + (bn + lr) * (long)K + lc;
    const bf16* Bg1 = Bg0 + 64L * K;

    bf16* lAd0 = lA + t * 8;
    bf16* lAd1 = lAd0 + 2048;
    bf16* lBd0 = lB + t * 8;
    bf16* lBd1 = lBd0 + 2048;

    f32x4 acc[4][4];
#pragma unroll
    for (int i = 0; i < 4; i++)
#pragma unroll
        for (int j = 0; j < 4; j++) acc[i][j] = (f32x4){0.f, 0.f, 0.f, 0.f};

    const int nk = K >> 5;
    for (int kt = 0; kt < nk; ++kt) {
        gload16(Ag0, lAd0);
        gload16(Ag1, lAd1);
        gload16(Bg0, lBd0);
        gload16(Bg1, lBd1);
        Ag0 += 32; Ag1 += 32; Bg0 += 32; Bg1 += 32;
        __syncthreads();

        short8 af[4], bv[4];
#pragma unroll
        for (int m = 0; m < 4; m++)
            af[m] = *(const short8*)(lA + (wr * 64 + m * 16 + fr) * 32 + kg * 8);
#pragma unroll
        for (int n = 0; n < 4; n++)
            bv[n] = *(const short8*)(lB + (wc * 64 + n * 16 + fr) * 32 + kg * 8);
#pragma unroll
        for (int m = 0; m < 4; m++)
#pragma unroll
            for (int n = 0; n < 4; n++)
                acc[m][n] = __builtin_amdgcn_mfma_f32_16x16x32_bf16(af[m], bv[n], acc[m][n], 0, 0, 0);
        __syncthreads();
    }

    // epilogue: C row = kg*4 + reg (+m*16), col = fr (+n*16)  [verified m89/m91]
#pragma unroll
    for (int m = 0; m < 4; m++) {
        const long row0 = bm + wr * 64 + m * 16 + kg * 4;
#pragma unroll
        for (int n = 0; n < 4; n++) {
            const long col = bn + wc * 64 + n * 16 + fr;
            const float bias_v = bias ? bias[col] : 0.0f;
#pragma unroll
            for (int r = 0; r < 4; r++) {
                float v = acc[m][n][r] + bias_v;
                if (GELU) v = gelu_f(v);
                const long idx = (row0 + r) * (long)N + col;
                if (OUTF) Cf[idx] = v;
                if (OUTB) Cb[idx] = __float2bfloat16(v);
            }
        }
    }
}

// Fused GEMM (N=512 fixed) + residual add + LayerNorm (+ optional 2nd LN).
// C = A(MxK) @ BT^T + bias; v = C + resid; y = LN(v; g1,b1); if DOUBLE_LN: y = LN(y; g2,b2).
// BM=64, BN=512, 512 threads / 8 waves; wave w owns 64 rows x 64 cols (col block w*64).
// acc[4][4] per thread = m97 MFMA density. Grid = M/64 = 256 blocks.
template<bool DOUBLE_LN, bool OUTF>
__global__ __launch_bounds__(512, 1)
void gemm_ln_kernel(const bf16* __restrict__ A, const bf16* __restrict__ BT,
                    const float* __restrict__ bias, const float* __restrict__ resid,
                    const float* __restrict__ g1, const float* __restrict__ b1,
                    const float* __restrict__ g2, const float* __restrict__ b2,
                    float* __restrict__ outf, bf16* __restrict__ outb,
                    int M, int K)
{
    __shared__ __align__(16) bf16 lA[64 * 32];     // 4 KB (reused as fp32 red[1024] in epilogue)
    __shared__ __align__(16) bf16 lB[512 * 32];    // 32 KB

    const int t    = threadIdx.x;
    const int lane = t & 63;
    const int w    = t >> 6;             // wave 0..7 -> col block w*64
    const int fr   = lane & 15, kg = lane >> 4;

    const int bid = xcd_swz(blockIdx.x, gridDim.x);
    const long bm = (long)bid * 64;

    const bf16* Ag = A + (bm + ((t >> 2) & 63)) * (long)K + (t & 3) * 8;  // guarded t<256
    const bf16* Bg = BT + (t >> 2) * (long)K + (t & 3) * 8;               // rows 0..127 (+i*128)

    f32x4 acc[4][4];
#pragma unroll
    for (int m = 0; m < 4; m++)
#pragma unroll
        for (int n = 0; n < 4; n++) acc[m][n] = (f32x4){0.f, 0.f, 0.f, 0.f};

    const int nk = K >> 5;
    for (int kt = 0; kt < nk; ++kt) {
        if (t < 256) gload16(Ag, lA + t * 8);          // 64x32 A-tile: 256 lanes x 16B
#pragma unroll
        for (int i = 0; i < 4; i++)                    // 512x32 B-tile: 4 x (512 lanes x 16B)
            gload16(Bg + (size_t)(i * 128) * K, lB + i * 4096 + t * 8);
        Ag += 32; Bg += 32;
        __syncthreads();

        short8 af[4], bv[4];
#pragma unroll
        for (int m = 0; m < 4; m++)
            af[m] = *(const short8*)(lA + (m * 16 + fr) * 32 + kg * 8);
#pragma unroll
        for (int n = 0; n < 4; n++)
            bv[n] = *(const short8*)(lB + (w * 64 + n * 16 + fr) * 32 + kg * 8);
#pragma unroll
        for (int m = 0; m < 4; m++)
#pragma unroll
            for (int n = 0; n < 4; n++)
                acc[m][n] = __builtin_amdgcn_mfma_f32_16x16x32_bf16(af[m], bv[n], acc[m][n], 0, 0, 0);
        __syncthreads();
    }

    // ---- epilogue: v = acc + bias + resid ----
    float bias_v[4];
#pragma unroll
    for (int n = 0; n < 4; n++) bias_v[n] = bias[w * 64 + n * 16 + fr];

#pragma unroll
    for (int m = 0; m < 4; m++)
#pragma unroll
        for (int r = 0; r < 4; r++) {
            const long row = bm + m * 16 + kg * 4 + r;
            const float* rr = resid + row * DM + w * 64 + fr;
#pragma unroll
            for (int n = 0; n < 4; n++)
                acc[m][n][r] += bias_v[n] + rr[n * 16];
        }

    float* red = (float*)lA;   // red[0..511]=S1 per (wave,row), red[512..1023]=S2

    float mean_[4][4], rstd_[4][4];
    // pass 1: mean/var of v over N=512 (8 wave-slices of 64 cols each)
    {
#pragma unroll
        for (int m = 0; m < 4; m++)
#pragma unroll
            for (int r = 0; r < 4; r++) {
                float s1 = 0.f, s2 = 0.f;
#pragma unroll
                for (int n = 0; n < 4; n++) { float v = acc[m][n][r]; s1 += v; s2 += v * v; }
#pragma unroll
                for (int mk = 1; mk <= 8; mk <<= 1) { s1 += __shfl_xor(s1, mk); s2 += __shfl_xor(s2, mk); }
                if (fr == 0) {
                    const int rw = m * 16 + kg * 4 + r;
                    red[w * 64 + rw] = s1;
                    red[512 + w * 64 + rw] = s2;
                }
            }
        __syncthreads();
#pragma unroll
        for (int m = 0; m < 4; m++)
#pragma unroll
            for (int r = 0; r < 4; r++) {
                const int rw = m * 16 + kg * 4 + r;
                float s1 = 0.f, s2 = 0.f;
#pragma unroll
                for (int ww = 0; ww < 8; ww++) {
                    s1 += red[ww * 64 + rw];
                    s2 += red[512 + ww * 64 + rw];
                }
                const float mu = s1 * (1.0f / 512.0f);
                mean_[m][r] = mu;
                rstd_[m][r] = rsqrtf(s2 * (1.0f / 512.0f) - mu * mu + EPSV);
            }
    }

    // y = (v - mu) * rstd * g1 + b1
    {
        float gv[4], bv1[4];
#pragma unroll
        for (int n = 0; n < 4; n++) {
            gv[n]  = g1[w * 64 + n * 16 + fr];
            bv1[n] = b1[w * 64 + n * 16 + fr];
        }
#pragma unroll
        for (int m = 0; m < 4; m++)
#pragma unroll
            for (int r = 0; r < 4; r++) {
                const float mu = mean_[m][r], rs = rstd_[m][r];
#pragma unroll
                for (int n = 0; n < 4; n++)
                    acc[m][n][r] = (acc[m][n][r] - mu) * rs * gv[n] + bv1[n];
            }
    }

    if (DOUBLE_LN) {
        __syncthreads();   // readers of red done before rewrite
#pragma unroll
        for (int m = 0; m < 4; m++)
#pragma unroll
            for (int r = 0; r < 4; r++) {
                float s1 = 0.f, s2 = 0.f;
#pragma unroll
                for (int n = 0; n < 4; n++) { float v = acc[m][n][r]; s1 += v; s2 += v * v; }
#pragma unroll
                for (int mk = 1; mk <= 8; mk <<= 1) { s1 += __shfl_xor(s1, mk); s2 += __shfl_xor(s2, mk); }
                if (fr == 0) {
                    const int rw = m * 16 + kg * 4 + r;
                    red[w * 64 + rw] = s1;
                    red[512 + w * 64 + rw] = s2;
                }
            }
        __syncthreads();
        float gv[4], bv2[4];
#pragma unroll
        for (int n = 0; n < 4; n++) {
            gv[n]  = g2[w * 64 + n * 16 + fr];
            bv2[n] = b2[w * 64 + n * 16 + fr];
        }
#pragma unroll
        for (int m = 0; m < 4; m++)
#pragma unroll
            for (int r = 0; r < 4; r++) {
                const int rw = m * 16 + kg * 4 + r;
                float s1 = 0.f, s2 = 0.f;
#pragma unroll
                for (int ww = 0; ww < 8; ww++) {
                    s1 += red[ww * 64 + rw];
                    s2 += red[512 + ww * 64 + rw];
                }
                const float mu = s1 * (1.0f / 512.0f);
                const float rs = rsqrtf(s2 * (1.0f / 512.0f) - mu * mu + EPSV);
#pragma unroll
                for (int n = 0; n < 4; n++)
                    acc[m][n][r] = (acc[m][n][r] - mu) * rs * gv[n] + bv2[n];
            }
    }

    // ---- write out ----
#pragma unroll
    for (int m = 0; m < 4; m++)
#pragma unroll
        for (int r = 0; r < 4; r++) {
            const long row = bm + m * 16 + kg * 4 + r;
            float* of = OUTF ? (outf + row * DM + w * 64 + fr) : nullptr;
            bf16* ob = outb + row * DM + w * 64 + fr;
#pragma unroll
            for (int n = 0; n < 4; n++) {
                const float v = acc[m][n][r];
                if (OUTF) of[n * 16] = v;
                ob[n * 16] = __float2bfloat16(v);
            }
        }
}

// src (K x N fp32, batched) -> dst (N x K bf16, batched)
__global__ __launch_bounds__(256)
void transpose_bf16_kernel(const float* __restrict__ src, bf16* __restrict__ dst, int K, int N)
{
    __shared__ float tile[32][33];
    const long boff = (long)blockIdx.z * K * N;
    src += boff; dst += boff;
    const int n0 = blockIdx.x * 32, k0 = blockIdx.y * 32;
    const int tx = threadIdx.x & 31, ty = threadIdx.x >> 5;  // 32x8
#pragma unroll
    for (int j = 0; j < 32; j += 8)
        tile[ty + j][tx] = src[(long)(k0 + ty + j) * N + n0 + tx];
    __syncthreads();
#pragma unroll
    for (int j = 0; j < 32; j += 8)
        dst[(long)(n0 + ty + j) * K + k0 + tx] = __float2bfloat16(tile[tx][ty + j]);
}

__global__ __launch_bounds__(256)
void cvt_kernel(const float* __restrict__ src, bf16* __restrict__ dst, long n4)
{
    const long i = (long)blockIdx.x * 256 + threadIdx.x;
    if (i >= n4) return;
    const float4 vv = *(const float4*)(src + i * 4);
    bf16 t[4] = {__float2bfloat16(vv.x), __float2bfloat16(vv.y),
                 __float2bfloat16(vv.z), __float2bfloat16(vv.w)};
    *(uint2*)(dst + i * 4) = *(const uint2*)t;
}

// b_a[n] = bo[n] + sum_j bv[j] * wo[j][n]
__global__ __launch_bounds__(256)
void ba_kernel(const float* __restrict__ bv, const float* __restrict__ wo,
               const float* __restrict__ bo, float* __restrict__ ba)
{
    const int n = blockIdx.x * 256 + threadIdx.x;  // 512 total
    float s = bo[n];
    for (int j = 0; j < DM; j++) s += bv[j] * wo[(long)j * DM + n];
    ba[n] = s;
}

extern "C" void kernel_launch(void* const* d_in, const int* in_sizes, int n_in,
                              void* d_out, int out_size, void* d_ws, size_t ws_size,
                              hipStream_t stream)
{
    const float* x       = (const float*)d_in[0];
    const float* w_in    = (const float*)d_in[1];
    const float* b_in    = (const float*)d_in[2];
    const float* wv      = (const float*)d_in[7];
    const float* bv      = (const float*)d_in[8];
    const float* wo      = (const float*)d_in[9];
    const float* bo      = (const float*)d_in[10];
    const float* conv1_w = (const float*)d_in[11];
    const float* conv1_b = (const float*)d_in[12];
    const float* conv2_w = (const float*)d_in[13];
    const float* conv2_b = (const float*)d_in[14];
    const float* n1_g    = (const float*)d_in[15];
    const float* n1_b    = (const float*)d_in[16];
    const float* n2_g    = (const float*)d_in[17];
    const float* n2_b    = (const float*)d_in[18];
    const float* norm_g  = (const float*)d_in[19];
    const float* norm_b  = (const float*)d_in[20];
    const float* w1      = (const float*)d_in[21];
    const float* b1      = (const float*)d_in[22];
    const float* w2      = (const float*)d_in[23];
    const float* b2      = (const float*)d_in[24];
    float* out = (float*)d_out;

    char* ws = (char*)d_ws;
    size_t off = 0;
    auto alloc = [&](size_t bytes) {
        char* p = ws + off;
        off += (bytes + 255) & ~(size_t)255;
        return p;
    };
    bf16*  xbf  = (bf16*) alloc((size_t)B_ROWS * DM * 2);
    float* h    = (float*)alloc((size_t)B_ROWS * DM * 4);
    bf16*  hbf  = (bf16*) alloc((size_t)B_ROWS * DM * 2);
    bf16*  y1   = (bf16*) alloc((size_t)B_ROWS * DFF * 2);
    bf16*  winT = (bf16*) alloc((size_t)DM * DM * 2);
    bf16*  woT  = (bf16*) alloc((size_t)DM * DM * 2);
    bf16*  wvbf = (bf16*) alloc((size_t)DM * DM * 2);
    bf16*  WaT  = (bf16*) alloc((size_t)DM * DM * 2);
    float* ba   = (float*)alloc((size_t)DM * 4);
    bf16*  c1T  = (bf16*) alloc((size_t)3 * DFF * DM * 2);
    bf16*  c2T  = (bf16*) alloc((size_t)3 * DM * DFF * 2);
    bf16*  w1T  = (bf16*) alloc((size_t)DFF * DM * 2);
    bf16*  w2T  = (bf16*) alloc((size_t)DOUT * DFF * 2);

    dim3 blk(256);

    // ---- prep: converts / transposes / folded attention weight ----
    cvt_kernel<<<(B_ROWS * DM / 4 + 255) / 256, blk, 0, stream>>>(x, xbf, (long)B_ROWS * DM / 4);
    cvt_kernel<<<(DM * DM / 4 + 255) / 256, blk, 0, stream>>>(wv, wvbf, (long)DM * DM / 4);
    transpose_bf16_kernel<<<dim3(DM / 32, DM / 32, 1), blk, 0, stream>>>(w_in, winT, DM, DM);
    transpose_bf16_kernel<<<dim3(DM / 32, DM / 32, 1), blk, 0, stream>>>(wo, woT, DM, DM);
    transpose_bf16_kernel<<<dim3(DFF / 32, DM / 32, 3), blk, 0, stream>>>(conv1_w, c1T, DM, DFF);
    transpose_bf16_kernel<<<dim3(DM / 32, DFF / 32, 3), blk, 0, stream>>>(conv2_w, c2T, DFF, DM);
    transpose_bf16_kernel<<<dim3(DFF / 32, DM / 32, 1), blk, 0, stream>>>(w1, w1T, DM, DFF);
    transpose_bf16_kernel<<<dim3(DOUT / 32, DFF / 32, 1), blk, 0, stream>>>(w2, w2T, DFF, DOUT);
    ba_kernel<<<2, blk, 0, stream>>>(bv, wo, bo, ba);
    // W_a^T = wo^T @ wv^T : A = woT, BT = wv. Output bf16 NxK form.
    gemm_kernel<false, false, true><<<dim3(4, 4), blk, 0, stream>>>(
        woT, wvbf, nullptr, nullptr, WaT, DM, DM, DM);

    // ---- h0 = x @ w_in + b_in ----
    gemm_kernel<false, true, true><<<dim3(4, 128), blk, 0, stream>>>(
        xbf, winT, b_in, h, hbf, B_ROWS, DM, DM);

    // ---- encoder layers (attn collapsed; LN fused into GEMM epilogues) ----
    for (int i = 0; i < 3; i++) {
        // h = LN1(h + hbf@Wa + ba)  -> writes h fp32 + hbf bf16
        gemm_ln_kernel<false, true><<<256, dim3(512), 0, stream>>>(
            hbf, WaT, ba, h, n1_g + i * DM, n1_b + i * DM, nullptr, nullptr,
            h, hbf, B_ROWS, DM);
        // y1 = gelu(hbf @ conv1 + b)
        gemm_kernel<true, false, true><<<dim3(16, 128), blk, 0, stream>>>(
            hbf, c1T + (size_t)i * DFF * DM, conv1_b + i * DFF, nullptr, y1, B_ROWS, DFF, DM);
        // h = LN2(h + y1@conv2 + b); layer 3 also applies final norm (double LN)
        if (i < 2) {
            gemm_ln_kernel<false, true><<<256, dim3(512), 0, stream>>>(
                y1, c2T + (size_t)i * DM * DFF, conv2_b + i * DM, h,
                n2_g + i * DM, n2_b + i * DM, nullptr, nullptr,
                h, hbf, B_ROWS, DFF);
        } else {
            gemm_ln_kernel<true, false><<<256, dim3(512), 0, stream>>>(
                y1, c2T + (size_t)i * DM * DFF, conv2_b + i * DM, h,
                n2_g + i * DM, n2_b + i * DM, norm_g, norm_b,
                nullptr, hbf, B_ROWS, DFF);
        }
    }

    // ---- head ----
    gemm_kernel<true, false, true><<<dim3(16, 128), blk, 0, stream>>>(
        hbf, w1T, b1, nullptr, y1, B_ROWS, DFF, DM);
    gemm_kernel<false, true, false><<<dim3(2, 128), blk, 0, stream>>>(
        y1, w2T, b2, out, nullptr, B_ROWS, DOUT, DFF);
}

// Round 6
// 789.297 us; speedup vs baseline: 1.0694x; 1.0694x over previous
//
#include <hip/hip_runtime.h>
#include <hip/hip_bf16.h>
#include <math.h>

#define B_ROWS 16384
#define DM 512
#define DFF 2048
#define DOUT 256
#define EPSV 1e-5f

typedef __hip_bfloat16 bf16;
typedef __attribute__((ext_vector_type(8))) short short8;
typedef __attribute__((ext_vector_type(4))) float f32x4;

__device__ __forceinline__ float gelu_f(float x) {
    return 0.5f * x * (1.0f + erff(x * 0.70710678118654752f));
}

__device__ __forceinline__ float bf2f(short s) {
    return __uint_as_float(((unsigned int)(unsigned short)s) << 16);
}

__device__ __forceinline__ void gload16(const void* g, void* l) {
    __builtin_amdgcn_global_load_lds((const __attribute__((address_space(1))) void*)g,
                                     (__attribute__((address_space(3))) void*)l, 16, 0, 0);
}

// bijective XCD swizzle; requires nwg % 8 == 0 (all our grids satisfy this)
__device__ __forceinline__ int xcd_swz(int bid, int nwg) {
    const int cpx = nwg >> 3;
    return (bid & 7) * cpx + (bid >> 3);
}

// C = A(MxK,row) @ B(KxN) + bias, B given as BT (NxK,row). bf16 in, fp32 accum.
// 128x128 tile, BK=32, 4 waves, mfma 16x16x32 bf16.
// 2-phase double-buffered pipeline: STAGE(buf^1, kt+1) issued BEFORE compute(buf),
// single barrier per K-step (compiler's pre-barrier vmcnt(0) completes the staged buf).
template<bool GELU, bool OUTF, bool OUTB>
__global__ __launch_bounds__(256, 2)
void gemm_kernel(const bf16* __restrict__ A, const bf16* __restrict__ BT,
                 const float* __restrict__ bias,
                 float* __restrict__ Cf, bf16* __restrict__ Cb,
                 int M, int N, int K)
{
    __shared__ __align__(16) bf16 lA[2][128 * 32];
    __shared__ __align__(16) bf16 lB[2][128 * 32];

    const int t    = threadIdx.x;
    const int lane = t & 63;
    const int w    = t >> 6;
    const int wr   = w >> 1, wc = w & 1;
    const int fr   = lane & 15, kg = lane >> 4;

    int bid = xcd_swz(blockIdx.y * gridDim.x + blockIdx.x, gridDim.x * gridDim.y);
    const int bx = bid % gridDim.x, by = bid / gridDim.x;
    const long bm = (long)by * 128;
    const long bn = (long)bx * 128;

    const int lr = t >> 2;           // 0..63
    const int lc = (t & 3) * 8;      // 0,8,16,24

    const bf16* Ag0 = A + (bm + lr) * (long)K + lc;
    const bf16* Ag1 = Ag0 + 64L * K;
    const bf16* Bg0 = BT + (bn + lr) * (long)K + lc;
    const bf16* Bg1 = Bg0 + 64L * K;

    f32x4 acc[4][4];
#pragma unroll
    for (int i = 0; i < 4; i++)
#pragma unroll
        for (int j = 0; j < 4; j++) acc[i][j] = (f32x4){0.f, 0.f, 0.f, 0.f};

    const int nk = K >> 5;

    // prologue: stage K-tile 0 into buf 0
    gload16(Ag0, &lA[0][t * 8]);
    gload16(Ag1, &lA[0][2048 + t * 8]);
    gload16(Bg0, &lB[0][t * 8]);
    gload16(Bg1, &lB[0][2048 + t * 8]);
    Ag0 += 32; Ag1 += 32; Bg0 += 32; Bg1 += 32;
    __syncthreads();   // vmcnt(0) drain -> buf0 ready

    int cur = 0;
    for (int kt = 0; kt < nk; ++kt) {
        // stage NEXT tile into the other buffer (loads fly during compute below)
        if (kt + 1 < nk) {
            const int nxt = cur ^ 1;
            gload16(Ag0, &lA[nxt][t * 8]);
            gload16(Ag1, &lA[nxt][2048 + t * 8]);
            gload16(Bg0, &lB[nxt][t * 8]);
            gload16(Bg1, &lB[nxt][2048 + t * 8]);
            Ag0 += 32; Ag1 += 32; Bg0 += 32; Bg1 += 32;
        }

        short8 af[4], bv[4];
#pragma unroll
        for (int m = 0; m < 4; m++)
            af[m] = *(const short8*)(&lA[cur][(wr * 64 + m * 16 + fr) * 32 + kg * 8]);
#pragma unroll
        for (int n = 0; n < 4; n++)
            bv[n] = *(const short8*)(&lB[cur][(wc * 64 + n * 16 + fr) * 32 + kg * 8]);
#pragma unroll
        for (int m = 0; m < 4; m++)
#pragma unroll
            for (int n = 0; n < 4; n++)
                acc[m][n] = __builtin_amdgcn_mfma_f32_16x16x32_bf16(af[m], bv[n], acc[m][n], 0, 0, 0);

        __syncthreads();   // drains vmcnt(0): next buf staged; all reads of cur done
        cur ^= 1;
    }

    // epilogue: C row = kg*4 + reg (+m*16), col = fr (+n*16)  [verified m89/m91]
#pragma unroll
    for (int m = 0; m < 4; m++) {
        const long row0 = bm + wr * 64 + m * 16 + kg * 4;
#pragma unroll
        for (int n = 0; n < 4; n++) {
            const long col = bn + wc * 64 + n * 16 + fr;
            const float bias_v = bias ? bias[col] : 0.0f;
#pragma unroll
            for (int r = 0; r < 4; r++) {
                float v = acc[m][n][r] + bias_v;
                if (GELU) v = gelu_f(v);
                const long idx = (row0 + r) * (long)N + col;
                if (OUTF) Cf[idx] = v;
                if (OUTB) Cb[idx] = __float2bfloat16(v);
            }
        }
    }
}

// LayerNorm over last dim (512). One wave per row, 4 rows/block.
// v = x (+ add, bf16); out = (v - mean)*rstd*g + b ; writes fp32 and/or bf16.
template<bool HASADD, bool OUTF>
__global__ __launch_bounds__(256)
void ln_kernel(const float* __restrict__ x, const bf16* __restrict__ add,
               const float* __restrict__ g, const float* __restrict__ bb,
               float* __restrict__ outf, bf16* __restrict__ outb)
{
    const int w    = threadIdx.x >> 6;
    const int lane = threadIdx.x & 63;
    const long row = (long)blockIdx.x * 4 + w;
    const int c0   = lane * 8;

    const float* xr = x + row * DM + c0;
    float4 a0 = *(const float4*)xr;
    float4 a1 = *(const float4*)(xr + 4);
    float v[8] = {a0.x, a0.y, a0.z, a0.w, a1.x, a1.y, a1.z, a1.w};
    if (HASADD) {
        short8 ad = *(const short8*)(add + row * DM + c0);
#pragma unroll
        for (int j = 0; j < 8; j++) v[j] += bf2f(ad[j]);
    }
    float s = 0.f;
#pragma unroll
    for (int j = 0; j < 8; j++) s += v[j];
#pragma unroll
    for (int off = 32; off > 0; off >>= 1) s += __shfl_xor(s, off);
    const float mean = s * (1.0f / 512.0f);

    float q = 0.f;
#pragma unroll
    for (int j = 0; j < 8; j++) { v[j] -= mean; q += v[j] * v[j]; }
#pragma unroll
    for (int off = 32; off > 0; off >>= 1) q += __shfl_xor(q, off);
    const float rstd = rsqrtf(q * (1.0f / 512.0f) + EPSV);

    float4 g0 = *(const float4*)(g + c0);
    float4 g1 = *(const float4*)(g + c0 + 4);
    float4 b0 = *(const float4*)(bb + c0);
    float4 b1 = *(const float4*)(bb + c0 + 4);
    float y[8];
    y[0] = v[0] * rstd * g0.x + b0.x; y[1] = v[1] * rstd * g0.y + b0.y;
    y[2] = v[2] * rstd * g0.z + b0.z; y[3] = v[3] * rstd * g0.w + b0.w;
    y[4] = v[4] * rstd * g1.x + b1.x; y[5] = v[5] * rstd * g1.y + b1.y;
    y[6] = v[6] * rstd * g1.z + b1.z; y[7] = v[7] * rstd * g1.w + b1.w;

    if (OUTF) {
        float* orow = outf + row * DM + c0;
        *(float4*)orow       = make_float4(y[0], y[1], y[2], y[3]);
        *(float4*)(orow + 4) = make_float4(y[4], y[5], y[6], y[7]);
    }
    {
        bf16 tmpb[8];
#pragma unroll
        for (int j = 0; j < 8; j++) tmpb[j] = __float2bfloat16(y[j]);
        *(uint4*)(outb + row * DM + c0) = *(const uint4*)tmpb;
    }
}

// src (K x N fp32, batched) -> dst (N x K bf16, batched)
__global__ __launch_bounds__(256)
void transpose_bf16_kernel(const float* __restrict__ src, bf16* __restrict__ dst, int K, int N)
{
    __shared__ float tile[32][33];
    const long boff = (long)blockIdx.z * K * N;
    src += boff; dst += boff;
    const int n0 = blockIdx.x * 32, k0 = blockIdx.y * 32;
    const int tx = threadIdx.x & 31, ty = threadIdx.x >> 5;  // 32x8
#pragma unroll
    for (int j = 0; j < 32; j += 8)
        tile[ty + j][tx] = src[(long)(k0 + ty + j) * N + n0 + tx];
    __syncthreads();
#pragma unroll
    for (int j = 0; j < 32; j += 8)
        dst[(long)(n0 + ty + j) * K + k0 + tx] = __float2bfloat16(tile[tx][ty + j]);
}

__global__ __launch_bounds__(256)
void cvt_kernel(const float* __restrict__ src, bf16* __restrict__ dst, long n4)
{
    const long i = (long)blockIdx.x * 256 + threadIdx.x;
    if (i >= n4) return;
    const float4 vv = *(const float4*)(src + i * 4);
    bf16 t[4] = {__float2bfloat16(vv.x), __float2bfloat16(vv.y),
                 __float2bfloat16(vv.z), __float2bfloat16(vv.w)};
    *(uint2*)(dst + i * 4) = *(const uint2*)t;
}

// b_a[n] = bo[n] + sum_j bv[j] * wo[j][n]
__global__ __launch_bounds__(256)
void ba_kernel(const float* __restrict__ bv, const float* __restrict__ wo,
               const float* __restrict__ bo, float* __restrict__ ba)
{
    const int n = blockIdx.x * 256 + threadIdx.x;  // 512 total
    float s = bo[n];
    for (int j = 0; j < DM; j++) s += bv[j] * wo[(long)j * DM + n];
    ba[n] = s;
}

extern "C" void kernel_launch(void* const* d_in, const int* in_sizes, int n_in,
                              void* d_out, int out_size, void* d_ws, size_t ws_size,
                              hipStream_t stream)
{
    const float* x       = (const float*)d_in[0];
    const float* w_in    = (const float*)d_in[1];
    const float* b_in    = (const float*)d_in[2];
    const float* wv      = (const float*)d_in[7];
    const float* bv      = (const float*)d_in[8];
    const float* wo      = (const float*)d_in[9];
    const float* bo      = (const float*)d_in[10];
    const float* conv1_w = (const float*)d_in[11];
    const float* conv1_b = (const float*)d_in[12];
    const float* conv2_w = (const float*)d_in[13];
    const float* conv2_b = (const float*)d_in[14];
    const float* n1_g    = (const float*)d_in[15];
    const float* n1_b    = (const float*)d_in[16];
    const float* n2_g    = (const float*)d_in[17];
    const float* n2_b    = (const float*)d_in[18];
    const float* norm_g  = (const float*)d_in[19];
    const float* norm_b  = (const float*)d_in[20];
    const float* w1      = (const float*)d_in[21];
    const float* b1      = (const float*)d_in[22];
    const float* w2      = (const float*)d_in[23];
    const float* b2      = (const float*)d_in[24];
    float* out = (float*)d_out;

    char* ws = (char*)d_ws;
    size_t off = 0;
    auto alloc = [&](size_t bytes) {
        char* p = ws + off;
        off += (bytes + 255) & ~(size_t)255;
        return p;
    };
    bf16*  xbf  = (bf16*) alloc((size_t)B_ROWS * DM * 2);
    float* h    = (float*)alloc((size_t)B_ROWS * DM * 4);
    bf16*  hbf  = (bf16*) alloc((size_t)B_ROWS * DM * 2);
    bf16*  tmpb = (bf16*) alloc((size_t)B_ROWS * DM * 2);
    bf16*  y1   = (bf16*) alloc((size_t)B_ROWS * DFF * 2);
    bf16*  winT = (bf16*) alloc((size_t)DM * DM * 2);
    bf16*  woT  = (bf16*) alloc((size_t)DM * DM * 2);
    bf16*  wvbf = (bf16*) alloc((size_t)DM * DM * 2);
    bf16*  WaT  = (bf16*) alloc((size_t)DM * DM * 2);
    float* ba   = (float*)alloc((size_t)DM * 4);
    bf16*  c1T  = (bf16*) alloc((size_t)3 * DFF * DM * 2);
    bf16*  c2T  = (bf16*) alloc((size_t)3 * DM * DFF * 2);
    bf16*  w1T  = (bf16*) alloc((size_t)DFF * DM * 2);
    bf16*  w2T  = (bf16*) alloc((size_t)DOUT * DFF * 2);

    dim3 blk(256);

    // ---- prep: converts / transposes / folded attention weight ----
    cvt_kernel<<<(B_ROWS * DM / 4 + 255) / 256, blk, 0, stream>>>(x, xbf, (long)B_ROWS * DM / 4);
    cvt_kernel<<<(DM * DM / 4 + 255) / 256, blk, 0, stream>>>(wv, wvbf, (long)DM * DM / 4);
    transpose_bf16_kernel<<<dim3(DM / 32, DM / 32, 1), blk, 0, stream>>>(w_in, winT, DM, DM);
    transpose_bf16_kernel<<<dim3(DM / 32, DM / 32, 1), blk, 0, stream>>>(wo, woT, DM, DM);
    transpose_bf16_kernel<<<dim3(DFF / 32, DM / 32, 3), blk, 0, stream>>>(conv1_w, c1T, DM, DFF);
    transpose_bf16_kernel<<<dim3(DM / 32, DFF / 32, 3), blk, 0, stream>>>(conv2_w, c2T, DFF, DM);
    transpose_bf16_kernel<<<dim3(DFF / 32, DM / 32, 1), blk, 0, stream>>>(w1, w1T, DM, DFF);
    transpose_bf16_kernel<<<dim3(DOUT / 32, DFF / 32, 1), blk, 0, stream>>>(w2, w2T, DFF, DOUT);
    ba_kernel<<<2, blk, 0, stream>>>(bv, wo, bo, ba);
    // W_a^T = wo^T @ wv^T : A = woT, BT = wv. Output bf16 NxK form.
    gemm_kernel<false, false, true><<<dim3(4, 4), blk, 0, stream>>>(
        woT, wvbf, nullptr, nullptr, WaT, DM, DM, DM);

    // ---- h0 = x @ w_in + b_in ----
    gemm_kernel<false, true, true><<<dim3(4, 128), blk, 0, stream>>>(
        xbf, winT, b_in, h, hbf, B_ROWS, DM, DM);

    // ---- encoder layers (attn collapsed; separate LN) ----
    for (int i = 0; i < 3; i++) {
        // tmpb = hbf @ Wa + ba (bf16)
        gemm_kernel<false, false, true><<<dim3(4, 128), blk, 0, stream>>>(
            hbf, WaT, ba, nullptr, tmpb, B_ROWS, DM, DM);
        // h = LN1(h + tmpb) -> h fp32 + hbf bf16
        ln_kernel<true, true><<<B_ROWS / 4, blk, 0, stream>>>(
            h, tmpb, n1_g + i * DM, n1_b + i * DM, h, hbf);
        // y1 = gelu(hbf @ conv1 + b)
        gemm_kernel<true, false, true><<<dim3(16, 128), blk, 0, stream>>>(
            hbf, c1T + (size_t)i * DFF * DM, conv1_b + i * DFF, nullptr, y1, B_ROWS, DFF, DM);
        // tmpb = y1 @ conv2 + b (bf16)
        gemm_kernel<false, false, true><<<dim3(4, 128), blk, 0, stream>>>(
            y1, c2T + (size_t)i * DM * DFF, conv2_b + i * DM, nullptr, tmpb, B_ROWS, DM, DFF);
        // h = LN2(h + tmpb)
        ln_kernel<true, true><<<B_ROWS / 4, blk, 0, stream>>>(
            h, tmpb, n2_g + i * DM, n2_b + i * DM, h, hbf);
    }

    // ---- final norm + head ----
    ln_kernel<false, false><<<B_ROWS / 4, blk, 0, stream>>>(
        h, nullptr, norm_g, norm_b, nullptr, hbf);
    gemm_kernel<true, false, true><<<dim3(16, 128), blk, 0, stream>>>(
        hbf, w1T, b1, nullptr, y1, B_ROWS, DFF, DM);
    gemm_kernel<false, true, false><<<dim3(2, 128), blk, 0, stream>>>(
        y1, w2T, b2, out, nullptr, B_ROWS, DOUT, DFF);
}